// Round 1
// baseline (8303.243 us; speedup 1.0000x reference)
//
#include <hip/hip_runtime.h>
#include <stddef.h>

#define NT 512      // timesteps
#define NI 28       // input dim
#define NH 64       // hidden dim
#define NG 256      // 4*NH gates
#define BT 8        // batch rows per block
#define CH 16       // timesteps of x staged per chunk
#define ROWF (CH*NI)  // 448 floats per (batch,chunk) row

__device__ __forceinline__ float fastrcp(float v) { return __builtin_amdgcn_rcpf(v); }
__device__ __forceinline__ float sigm(float v)   { return fastrcp(1.f + __expf(-v)); }
// tanh via exp, saturates correctly at +/-1 for large |v| (no inf/inf NaN)
__device__ __forceinline__ float tanh_(float v)  { return 1.f - 2.f*fastrcp(__expf(2.f*v) + 1.f); }

__global__ __launch_bounds__(256, 1)
void lstm2_kernel(const float* __restrict__ x,
                  const float* __restrict__ Wih0, const float* __restrict__ Whh0,
                  const float* __restrict__ bih0, const float* __restrict__ bhh0,
                  const float* __restrict__ Wih1, const float* __restrict__ Whh1,
                  const float* __restrict__ bih1, const float* __restrict__ bhh1,
                  const float* __restrict__ Wout, const float* __restrict__ bout,
                  float* __restrict__ out, float* __restrict__ rlast)
{
    __shared__ __align__(16) float s_x[BT][ROWF];   // staged x chunk
    __shared__ __align__(16) float s_h0[BT][NH];    // layer0 hidden
    __shared__ __align__(16) float s_h1[BT][NH];    // layer1 hidden
    __shared__ __align__(16) float s_g[BT][NG];     // gate scratch

    const int j  = threadIdx.x;          // gate row 0..255 (PyTorch order i,f,g,o blocks)
    const int b0 = blockIdx.x * BT;

    // ---- per-thread weight rows in registers (constant-indexed, fully unrolled) ----
    float wi0[NI], wh0[NH], wi1[NH], wh1[NH];
    {
        const float4* p = (const float4*)(Wih0 + j*NI);   // 28 floats -> 7 float4, 16B aligned
        #pragma unroll
        for (int k = 0; k < NI/4; ++k) { float4 v = p[k];
            wi0[4*k]=v.x; wi0[4*k+1]=v.y; wi0[4*k+2]=v.z; wi0[4*k+3]=v.w; }
    }
    {
        const float4* p = (const float4*)(Whh0 + j*NH);
        #pragma unroll
        for (int k = 0; k < NH/4; ++k) { float4 v = p[k];
            wh0[4*k]=v.x; wh0[4*k+1]=v.y; wh0[4*k+2]=v.z; wh0[4*k+3]=v.w; }
    }
    {
        const float4* p = (const float4*)(Wih1 + j*NH);
        #pragma unroll
        for (int k = 0; k < NH/4; ++k) { float4 v = p[k];
            wi1[4*k]=v.x; wi1[4*k+1]=v.y; wi1[4*k+2]=v.z; wi1[4*k+3]=v.w; }
    }
    {
        const float4* p = (const float4*)(Whh1 + j*NH);
        #pragma unroll
        for (int k = 0; k < NH/4; ++k) { float4 v = p[k];
            wh1[4*k]=v.x; wh1[4*k+1]=v.y; wh1[4*k+2]=v.z; wh1[4*k+3]=v.w; }
    }
    const float bias0 = bih0[j] + bhh0[j];
    const float bias1 = bih1[j] + bhh1[j];

    const int uu = j & (NH-1);   // hidden unit this thread updates
    const int bb = j >> 6;       // batch row 0..3 (also handles bb+4)

    s_h0[bb][uu] = 0.f; s_h0[bb+4][uu] = 0.f;
    s_h1[bb][uu] = 0.f; s_h1[bb+4][uu] = 0.f;
    float c0A = 0.f, c0B = 0.f, c1A = 0.f, c1B = 0.f;   // cell states in registers
    __syncthreads();

    for (int tc = 0; tc < NT; tc += CH) {
        // ---- stage x[b0..b0+7][tc..tc+CH) into LDS, coalesced float4 ----
        const float4* xg4 = (const float4*)x;
        #pragma unroll 1
        for (int idx = j; idx < BT*(ROWF/4); idx += NG) {
            int b = idx / (ROWF/4);
            int o = idx - b*(ROWF/4);
            float4 v = xg4[((size_t)(b0+b)*NT*NI + (size_t)tc*NI)/4 + o];
            ((float4*)&s_x[b][0])[o] = v;
        }
        __syncthreads();

        for (int tt = 0; tt < CH; ++tt) {
            // ---------------- layer 0 gates ----------------
            float acc[BT];
            #pragma unroll
            for (int b = 0; b < BT; ++b) acc[b] = bias0;
            #pragma unroll
            for (int k = 0; k < NI; ++k) {
                #pragma unroll
                for (int b = 0; b < BT; ++b) acc[b] += wi0[k] * s_x[b][tt*NI + k];
            }
            #pragma unroll
            for (int k = 0; k < NH; ++k) {
                #pragma unroll
                for (int b = 0; b < BT; ++b) acc[b] += wh0[k] * s_h0[b][k];
            }
            #pragma unroll
            for (int b = 0; b < BT; ++b) s_g[b][j] = acc[b];
            __syncthreads();

            // ---------------- layer 0 update ----------------
            {
                float gi = s_g[bb][uu],      gf = s_g[bb][NH+uu];
                float gg = s_g[bb][2*NH+uu], go = s_g[bb][3*NH+uu];
                float ii = sigm(gi), ff = sigm(gf), g_ = tanh_(gg), oo = sigm(go);
                c0A = ff*c0A + ii*g_;
                s_h0[bb][uu] = oo * tanh_(c0A);
            }
            {
                float gi = s_g[bb+4][uu],      gf = s_g[bb+4][NH+uu];
                float gg = s_g[bb+4][2*NH+uu], go = s_g[bb+4][3*NH+uu];
                float ii = sigm(gi), ff = sigm(gf), g_ = tanh_(gg), oo = sigm(go);
                c0B = ff*c0B + ii*g_;
                s_h0[bb+4][uu] = oo * tanh_(c0B);
            }
            __syncthreads();

            // ---------------- layer 1 gates ----------------
            #pragma unroll
            for (int b = 0; b < BT; ++b) acc[b] = bias1;
            #pragma unroll
            for (int k = 0; k < NH; ++k) {
                #pragma unroll
                for (int b = 0; b < BT; ++b) acc[b] += wi1[k] * s_h0[b][k];
            }
            #pragma unroll
            for (int k = 0; k < NH; ++k) {
                #pragma unroll
                for (int b = 0; b < BT; ++b) acc[b] += wh1[k] * s_h1[b][k];
            }
            #pragma unroll
            for (int b = 0; b < BT; ++b) s_g[b][j] = acc[b];
            __syncthreads();

            // ---------------- layer 1 update ----------------
            {
                float gi = s_g[bb][uu],      gf = s_g[bb][NH+uu];
                float gg = s_g[bb][2*NH+uu], go = s_g[bb][3*NH+uu];
                float ii = sigm(gi), ff = sigm(gf), g_ = tanh_(gg), oo = sigm(go);
                c1A = ff*c1A + ii*g_;
                s_h1[bb][uu] = oo * tanh_(c1A);
            }
            {
                float gi = s_g[bb+4][uu],      gf = s_g[bb+4][NH+uu];
                float gg = s_g[bb+4][2*NH+uu], go = s_g[bb+4][3*NH+uu];
                float ii = sigm(gi), ff = sigm(gf), g_ = tanh_(gg), oo = sigm(go);
                c1B = ff*c1B + ii*g_;
                s_h1[bb+4][uu] = oo * tanh_(c1B);
            }
            __syncthreads();
        }
    }

    // ---------------- epilogue ----------------
    // r_last = h1 at t = T-1  (output 1, at offset 2048*10 in d_out)
    rlast[(size_t)(b0+bb)*NH + uu]   = s_h1[bb][uu];
    rlast[(size_t)(b0+bb+4)*NH + uu] = s_h1[bb+4][uu];
    // out = r_last @ Wout.T + bout  (output 0)
    if (j < BT*10) {
        int b = j / 10, o = j - 10*(j/10);
        float a = bout[o];
        #pragma unroll
        for (int u = 0; u < NH; ++u) a += Wout[o*NH + u] * s_h1[b][u];
        out[(size_t)(b0+b)*10 + o] = a;
    }
}

extern "C" void kernel_launch(void* const* d_in, const int* in_sizes, int n_in,
                              void* d_out, int out_size, void* d_ws, size_t ws_size,
                              hipStream_t stream) {
    const float* x    = (const float*)d_in[0];
    const float* Wih0 = (const float*)d_in[1];
    const float* Whh0 = (const float*)d_in[2];
    const float* bih0 = (const float*)d_in[3];
    const float* bhh0 = (const float*)d_in[4];
    const float* Wih1 = (const float*)d_in[5];
    const float* Whh1 = (const float*)d_in[6];
    const float* bih1 = (const float*)d_in[7];
    const float* bhh1 = (const float*)d_in[8];
    const float* Wout = (const float*)d_in[9];
    const float* bout = (const float*)d_in[10];

    const int B = in_sizes[0] / (NT * NI);      // 2048
    float* out   = (float*)d_out;               // [B,10]
    float* rlast = out + (size_t)B * 10;        // [B,64]

    dim3 grid(B / BT), block(NG);
    hipLaunchKernelGGL(lstm2_kernel, grid, block, 0, stream,
                       x, Wih0, Whh0, bih0, bhh0, Wih1, Whh1, bih1, bhh1,
                       Wout, bout, out, rlast);
}

// Round 2
// 2084.056 us; speedup vs baseline: 3.9842x; 3.9842x over previous
//
#include <hip/hip_runtime.h>
#include <stddef.h>

#define NT 512       // timesteps
#define NI 28        // input dim
#define NH 64        // hidden dim
#define NG 256       // 4*NH gate rows
#define BT 8         // batch rows per block
#define CH 16        // timesteps of x staged per chunk
#define XPITCH 32    // padded floats per timestep in LDS (28 payload + 4 zero pad)
#define NTH 512      // threads per block = 256 gate rows x 2 k-halves

__device__ __forceinline__ float sigm(float v)  { return __builtin_amdgcn_rcpf(1.f + __expf(-v)); }
// tanh via exp; saturates correctly at +/-1 for large |v|
__device__ __forceinline__ float tanh_(float v) { return 1.f - 2.f * __builtin_amdgcn_rcpf(__expf(2.f * v) + 1.f); }

__global__ __launch_bounds__(NTH, 2)
void lstm2_kernel(const float* __restrict__ x,
                  const float* __restrict__ Wih0, const float* __restrict__ Whh0,
                  const float* __restrict__ bih0, const float* __restrict__ bhh0,
                  const float* __restrict__ Wih1, const float* __restrict__ Whh1,
                  const float* __restrict__ bih1, const float* __restrict__ bhh1,
                  const float* __restrict__ Wout, const float* __restrict__ bout,
                  float* __restrict__ out, float* __restrict__ rlast)
{
    __shared__ __align__(16) float s_x[BT][CH * XPITCH];  // 16 KB staged x chunk (padded)
    __shared__ __align__(16) float s_h[2][BT][NH];        // h per layer
    __shared__ __align__(16) float s_g[2][BT][NG];        // gates per layer (layer1 skewed -1)

    const int tid = threadIdx.x;
    const int j   = tid >> 1;       // gate row 0..255 (PyTorch order: i,f,g,o blocks of 64)
    const int hf  = tid & 1;        // k-half: 0 -> k[0..31], 1 -> k[32..63] (x: 0..15 / 16..27)
    const int b0  = blockIdx.x * BT;
    const int hoff = hf * 32;

    // ---- per-thread weight half-rows in registers (constant-indexed, unrolled) ----
    float wx[16], wh0r[32], wi1r[32], wh1r[32];
    #pragma unroll
    for (int k = 0; k < 16; ++k) {
        float v = 0.f;
        if (!(hf && k >= 12)) v = Wih0[j * NI + hf * 16 + k];  // guard OOB for hf=1,k>=12
        wx[k] = v;
    }
    #pragma unroll
    for (int k = 0; k < 32; ++k) wh0r[k] = Whh0[j * NH + hoff + k];
    #pragma unroll
    for (int k = 0; k < 32; ++k) wi1r[k] = Wih1[j * NH + hoff + k];
    #pragma unroll
    for (int k = 0; k < 32; ++k) wh1r[k] = Whh1[j * NH + hoff + k];

    float bias_;
    if (hf) bias_ = bih1[j] + bhh1[j];
    else    bias_ = bih0[j] + bhh0[j];
    const float binit0 = hf ? 0.f : bias_;   // even lane carries layer0 bias in its partial
    const float binit1 = hf ? bias_ : 0.f;   // odd lane carries layer1 bias

    // ---- cell ownership: thread updates 2 cells of layer `lay=hf`: (bb,uu) and (bb+4,uu) ----
    const int lay = hf;
    const int uu  = (tid >> 1) & (NH - 1);
    const int bb  = (tid >> 7) & 3;
    float cA = 0.f, cB = 0.f;

    // zero h
    #pragma unroll
    for (int i = tid; i < 2 * BT * NH; i += NTH) ((float*)s_h)[i] = 0.f;

    const float4* xg4 = (const float4*)x;

    // Pipeline: iteration n computes g0(n) [n<NT] and g1(n-1) [n>=1] in one phase,
    // then updates h0(n) and h1(n-1). 2 barriers per iteration.
    for (int n = 0; n <= NT; ++n) {
        // ---- stage x chunk every CH steps (phase-B of prev iter never reads s_x) ----
        if (((n & (CH - 1)) == 0) && n < NT) {
            #pragma unroll 1
            for (int idx = tid; idx < BT * CH * (NI / 4); idx += NTH) {  // 896 float4
                int b = idx / (CH * (NI / 4));
                int o = idx - b * (CH * (NI / 4));
                int t = o / (NI / 4);
                int w = o - t * (NI / 4);
                float4 v = xg4[((size_t)(b0 + b) * NT + n) * (NI / 4) + o];
                ((float4*)&s_x[b][0])[t * (XPITCH / 4) + w] = v;
            }
            #pragma unroll 1
            for (int idx = tid; idx < BT * CH; idx += NTH) {  // zero the pad slot
                int b = idx >> 4, t = idx & (CH - 1);
                ((float4*)&s_x[b][0])[t * (XPITCH / 4) + (NI / 4)] = make_float4(0.f, 0.f, 0.f, 0.f);
            }
        }
        __syncthreads();   // orders: staging + prev h-updates  before  gate reads

        // ---------------- phase A: partial gate sums ----------------
        const int tt = n & (CH - 1);
        float acc0[BT], acc1[BT];
        #pragma unroll
        for (int b = 0; b < BT; ++b) { acc0[b] = binit0; acc1[b] = binit1; }

        const int xbase = tt * XPITCH + hf * 16;
        #pragma unroll
        for (int k4 = 0; k4 < 4; ++k4) {
            #pragma unroll
            for (int b = 0; b < BT; ++b) {
                const float4 v = *(const float4*)&s_x[b][xbase + 4 * k4];
                acc0[b] += wx[4 * k4 + 0] * v.x;
                acc0[b] += wx[4 * k4 + 1] * v.y;
                acc0[b] += wx[4 * k4 + 2] * v.z;
                acc0[b] += wx[4 * k4 + 3] * v.w;
            }
        }
        #pragma unroll
        for (int k4 = 0; k4 < 8; ++k4) {
            #pragma unroll
            for (int b = 0; b < BT; ++b) {
                const float4 h0v = *(const float4*)&s_h[0][b][hoff + 4 * k4];
                const float4 h1v = *(const float4*)&s_h[1][b][hoff + 4 * k4];
                acc0[b] += wh0r[4 * k4 + 0] * h0v.x;
                acc0[b] += wh0r[4 * k4 + 1] * h0v.y;
                acc0[b] += wh0r[4 * k4 + 2] * h0v.z;
                acc0[b] += wh0r[4 * k4 + 3] * h0v.w;
                acc1[b] += wi1r[4 * k4 + 0] * h0v.x;
                acc1[b] += wi1r[4 * k4 + 1] * h0v.y;
                acc1[b] += wi1r[4 * k4 + 2] * h0v.z;
                acc1[b] += wi1r[4 * k4 + 3] * h0v.w;
                acc1[b] += wh1r[4 * k4 + 0] * h1v.x;
                acc1[b] += wh1r[4 * k4 + 1] * h1v.y;
                acc1[b] += wh1r[4 * k4 + 2] * h1v.z;
                acc1[b] += wh1r[4 * k4 + 3] * h1v.w;
            }
        }
        // combine k-halves: even lane ends with full g0(n), odd lane with full g1(n-1)
        #pragma unroll
        for (int b = 0; b < BT; ++b) {
            float mine  = hf ? acc1[b] : acc0[b];
            float sendv = hf ? acc0[b] : acc1[b];
            float got   = __shfl_xor(sendv, 1, 64);
            s_g[hf][b][j] = mine + got;
        }
        __syncthreads();

        // ---------------- phase B: cell updates ----------------
        const bool doit = lay ? (n >= 1) : (n < NT);
        if (doit) {
            {
                float gi = s_g[lay][bb][uu];
                float gf = s_g[lay][bb][NH + uu];
                float gg = s_g[lay][bb][2 * NH + uu];
                float go = s_g[lay][bb][3 * NH + uu];
                float ii = sigm(gi), ff = sigm(gf), g_ = tanh_(gg), oo = sigm(go);
                cA = ff * cA + ii * g_;
                s_h[lay][bb][uu] = oo * tanh_(cA);
            }
            {
                float gi = s_g[lay][bb + 4][uu];
                float gf = s_g[lay][bb + 4][NH + uu];
                float gg = s_g[lay][bb + 4][2 * NH + uu];
                float go = s_g[lay][bb + 4][3 * NH + uu];
                float ii = sigm(gi), ff = sigm(gf), g_ = tanh_(gg), oo = sigm(go);
                cB = ff * cB + ii * g_;
                s_h[lay][bb + 4][uu] = oo * tanh_(cB);
            }
        }
        __syncthreads();
    }

    // ---------------- epilogue (last sync above covers s_h[1] writes) ----------------
    #pragma unroll 1
    for (int idx = tid; idx < BT * NH; idx += NTH)  // exactly 512
        rlast[(size_t)(b0 + (idx >> 6)) * NH + (idx & 63)] = s_h[1][idx >> 6][idx & 63];

    if (tid < BT * 10) {
        int b = tid / 10, o = tid - 10 * (tid / 10);
        float a = bout[o];
        #pragma unroll
        for (int u = 0; u < NH; ++u) a += Wout[o * NH + u] * s_h[1][b][u];
        out[(size_t)(b0 + b) * 10 + o] = a;
    }
}

extern "C" void kernel_launch(void* const* d_in, const int* in_sizes, int n_in,
                              void* d_out, int out_size, void* d_ws, size_t ws_size,
                              hipStream_t stream) {
    const float* x    = (const float*)d_in[0];
    const float* Wih0 = (const float*)d_in[1];
    const float* Whh0 = (const float*)d_in[2];
    const float* bih0 = (const float*)d_in[3];
    const float* bhh0 = (const float*)d_in[4];
    const float* Wih1 = (const float*)d_in[5];
    const float* Whh1 = (const float*)d_in[6];
    const float* bih1 = (const float*)d_in[7];
    const float* bhh1 = (const float*)d_in[8];
    const float* Wout = (const float*)d_in[9];
    const float* bout = (const float*)d_in[10];

    const int B = in_sizes[0] / (NT * NI);      // 2048
    float* out   = (float*)d_out;               // [B,10]
    float* rlast = out + (size_t)B * 10;        // [B,64]

    dim3 grid(B / BT), block(NTH);
    hipLaunchKernelGGL(lstm2_kernel, grid, block, 0, stream,
                       x, Wih0, Whh0, bih0, bhh0, Wih1, Whh1, bih1, bhh1,
                       Wout, bout, out, rlast);
}

// Round 3
// 926.150 us; speedup vs baseline: 8.9653x; 2.2502x over previous
//
#include <hip/hip_runtime.h>
#include <stddef.h>

#define NT 512       // timesteps
#define NI 28        // input dim
#define NH 64        // hidden dim
#define BT 8         // batch rows per block
#define CH 16        // x timesteps staged per chunk
#define XP 40        // shorts per (t,b) x row  (28 + pad; 80B -> bank-stride 20 dw)
#define HP 136       // shorts per b h row (h0|h1 = 128 + 8 pad; 272B -> stride 4 dw)
#define GP 260       // floats per (lay,b) gate row (256 + 4 pad)
#define NTH 512      // 8 waves

typedef short bf16x8 __attribute__((ext_vector_type(8)));
typedef float f32x4  __attribute__((ext_vector_type(4)));

__device__ __forceinline__ short f2bf(float f) {         // fp32 -> bf16 RNE
    unsigned u = __float_as_uint(f);
    u += 0x7FFF + ((u >> 16) & 1);
    return (short)(u >> 16);
}
__device__ __forceinline__ float bf2f(short s) {
    return __uint_as_float(((unsigned)(unsigned short)s) << 16);
}
__device__ __forceinline__ float sigm(float v)  { return __builtin_amdgcn_rcpf(1.f + __expf(-v)); }
__device__ __forceinline__ float tanh_(float v) { return 1.f - 2.f * __builtin_amdgcn_rcpf(__expf(2.f * v) + 1.f); }

__global__ __launch_bounds__(NTH, 2)
void lstm2_mfma(const float* __restrict__ x,
                const float* __restrict__ Wih0, const float* __restrict__ Whh0,
                const float* __restrict__ bih0, const float* __restrict__ bhh0,
                const float* __restrict__ Wih1, const float* __restrict__ Whh1,
                const float* __restrict__ bih1, const float* __restrict__ bhh1,
                const float* __restrict__ Wout, const float* __restrict__ bout,
                float* __restrict__ out, float* __restrict__ rlast)
{
    __shared__ __align__(16) short s_xhi[CH * BT * XP], s_xlo[CH * BT * XP];
    __shared__ __align__(16) short s_hhi[BT * HP],      s_hlo[BT * HP];
    __shared__ __align__(16) float s_g[2 * BT * GP];

    const int tid = threadIdx.x;
    const int ln  = tid & 63;
    const int wv  = tid >> 6;        // wave 0..7
    const int lay = wv >> 2;         // 0: layer0 gate waves, 1: layer1
    const int w4  = wv & 3;          // 64-gate slice within layer
    const int b0  = blockIdx.x * BT;

    const int colB = ln & 15;        // n within 16-tile (B/D col, A row)
    const int kq   = (ln >> 4) * 8;  // k-offset of this lane's 8 elements
    const int bA   = ln & 7;         // batch row for A operand (rows 8-15 dup)

    // ---------------- B fragments: weights -> split bf16, held in registers ----------------
    // B layout: lane holds B[k = kq+j][n = colB] = W[n][koff+kq+j], 8 k-consecutive.
    bf16x8 Bh[4][4], Bl[4][4];
    float  biasf[4];
    #pragma unroll
    for (int t = 0; t < 4; ++t) {
        const int n = w4 * 64 + t * 16 + colB;
        biasf[t] = lay ? (bih1[n] + bhh1[n]) : (bih0[n] + bhh0[n]);
        #pragma unroll
        for (int c = 0; c < 4; ++c) {
            const float* src; int koff, klen;
            if (lay == 0) {
                if      (c == 0) { src = Wih0 + n * NI; koff = 0;  klen = NI; }
                else if (c == 1) { src = Whh0 + n * NH; koff = 0;  klen = NH; }
                else if (c == 2) { src = Whh0 + n * NH; koff = 32; klen = NH; }
                else             { src = Whh0 + n * NH; koff = 0;  klen = 0;  } // zero chunk
            } else {
                if      (c == 0) { src = Wih1 + n * NH; koff = 0;  klen = NH; }
                else if (c == 1) { src = Wih1 + n * NH; koff = 32; klen = NH; }
                else if (c == 2) { src = Whh1 + n * NH; koff = 0;  klen = NH; }
                else             { src = Whh1 + n * NH; koff = 32; klen = NH; }
            }
            #pragma unroll
            for (int j = 0; j < 8; ++j) {
                int k = koff + kq + j;
                float w = (k < klen) ? src[k] : 0.f;
                short h = f2bf(w);
                Bh[t][c][j] = h;
                Bl[t][c][j] = f2bf(w - bf2f(h));
            }
        }
    }

    // ---------------- zero h state and x pad columns ----------------
    #pragma unroll 1
    for (int i = tid; i < BT * HP; i += NTH) { s_hhi[i] = 0; s_hlo[i] = 0; }
    #pragma unroll 1
    for (int i = tid; i < CH * BT * (XP - NI); i += NTH) {
        int t = i / (BT * (XP - NI));
        int r = i - t * (BT * (XP - NI));
        int b = r / (XP - NI);
        int k = NI + (r - b * (XP - NI));
        s_xhi[(t * BT + b) * XP + k] = 0;
        s_xlo[(t * BT + b) * XP + k] = 0;
    }

    const short* hhi_p = s_hhi + bA * HP + kq;
    const short* hlo_p = s_hlo + bA * HP + kq;
    const int be = tid >> 6, ue = tid & 63;   // elementwise cell (batch, unit)
    float c0 = 0.f, c1 = 0.f;

    const float4* xg4 = (const float4*)x;

    // Skewed pipeline: iter n computes g0(n) [n<NT] and g1(n-1) [n>=1]; then
    // elementwise updates h0(n) and h1(n-1). 2 barriers/iter.
    for (int n = 0; n <= NT; ++n) {
        if ((n & (CH - 1)) == 0 && n < NT) {
            #pragma unroll 1
            for (int idx = tid; idx < BT * CH * (NI / 4); idx += NTH) {  // 896 float4
                int b  = idx / (CH * (NI / 4));
                int r  = idx - b * (CH * (NI / 4));
                int t  = r / (NI / 4);
                int w7 = r - t * (NI / 4);
                float4 v = xg4[((size_t)(b0 + b) * NT + n + t) * (NI / 4) + w7];
                int base = (t * BT + b) * XP + 4 * w7;
                short h;
                h = f2bf(v.x); s_xhi[base + 0] = h; s_xlo[base + 0] = f2bf(v.x - bf2f(h));
                h = f2bf(v.y); s_xhi[base + 1] = h; s_xlo[base + 1] = f2bf(v.y - bf2f(h));
                h = f2bf(v.z); s_xhi[base + 2] = h; s_xlo[base + 2] = f2bf(v.z - bf2f(h));
                h = f2bf(v.w); s_xhi[base + 3] = h; s_xlo[base + 3] = f2bf(v.w - bf2f(h));
            }
        }
        __syncthreads();   // staging + prev h-writes visible

        // ---------------- MFMA phase ----------------
        if (!(lay == 0 && n == NT)) {
            bf16x8 Ah[4], Al[4];
            const int tt = n & (CH - 1);
            if (lay == 0) {
                const short* xp = s_xhi + (tt * BT + bA) * XP + kq;
                const short* xq = s_xlo + (tt * BT + bA) * XP + kq;
                Ah[0] = *(const bf16x8*)xp;          Al[0] = *(const bf16x8*)xq;
                Ah[1] = *(const bf16x8*)(hhi_p);     Al[1] = *(const bf16x8*)(hlo_p);
                Ah[2] = *(const bf16x8*)(hhi_p + 32); Al[2] = *(const bf16x8*)(hlo_p + 32);
                Ah[3] = Ah[2];                        Al[3] = Al[2];   // paired with zero B
            } else {
                Ah[0] = *(const bf16x8*)(hhi_p);      Al[0] = *(const bf16x8*)(hlo_p);
                Ah[1] = *(const bf16x8*)(hhi_p + 32); Al[1] = *(const bf16x8*)(hlo_p + 32);
                Ah[2] = *(const bf16x8*)(hhi_p + 64); Al[2] = *(const bf16x8*)(hlo_p + 64);
                Ah[3] = *(const bf16x8*)(hhi_p + 96); Al[3] = *(const bf16x8*)(hlo_p + 96);
            }
            #pragma unroll
            for (int t = 0; t < 4; ++t) {
                f32x4 acc = { biasf[t], biasf[t], biasf[t], biasf[t] };
                #pragma unroll
                for (int c = 0; c < 4; ++c) {
                    acc = __builtin_amdgcn_mfma_f32_16x16x32_bf16(Ah[c], Bh[t][c], acc, 0, 0, 0);
                    acc = __builtin_amdgcn_mfma_f32_16x16x32_bf16(Ah[c], Bl[t][c], acc, 0, 0, 0);
                    acc = __builtin_amdgcn_mfma_f32_16x16x32_bf16(Al[c], Bh[t][c], acc, 0, 0, 0);
                }
                // D layout: col = ln&15, row = (ln>>4)*4 + r ; rows 0..7 valid
                if (ln < 32) {
                    const int m0 = (ln >> 4) * 4;
                    const int nn = w4 * 64 + t * 16 + colB;
                    #pragma unroll
                    for (int r = 0; r < 4; ++r)
                        s_g[(lay * BT + m0 + r) * GP + nn] = acc[r];
                }
            }
        }
        __syncthreads();   // gates visible

        // ---------------- elementwise phase ----------------
        if (n < NT) {      // layer0 update: h0(n)
            float gi = s_g[(0 * BT + be) * GP + ue];
            float gf = s_g[(0 * BT + be) * GP + 64 + ue];
            float gg = s_g[(0 * BT + be) * GP + 128 + ue];
            float go = s_g[(0 * BT + be) * GP + 192 + ue];
            float ii = sigm(gi), ff = sigm(gf), g_ = tanh_(gg), oo = sigm(go);
            c0 = ff * c0 + ii * g_;
            float h0f = oo * tanh_(c0);
            short hh = f2bf(h0f);
            s_hhi[be * HP + ue] = hh;
            s_hlo[be * HP + ue] = f2bf(h0f - bf2f(hh));
        }
        if (n > 0) {       // layer1 update: h1(n-1)
            float gi = s_g[(1 * BT + be) * GP + ue];
            float gf = s_g[(1 * BT + be) * GP + 64 + ue];
            float gg = s_g[(1 * BT + be) * GP + 128 + ue];
            float go = s_g[(1 * BT + be) * GP + 192 + ue];
            float ii = sigm(gi), ff = sigm(gf), g_ = tanh_(gg), oo = sigm(go);
            c1 = ff * c1 + ii * g_;
            float h1f = oo * tanh_(c1);
            short hh = f2bf(h1f);
            s_hhi[be * HP + 64 + ue] = hh;
            s_hlo[be * HP + 64 + ue] = f2bf(h1f - bf2f(hh));
            if (n == NT) {
                rlast[(size_t)(b0 + be) * NH + ue] = h1f;
                s_g[(0 * BT + be) * GP + ue] = h1f;   // fp32 stash for head (layer0 slot idle)
            }
        }
    }
    __syncthreads();

    // ---------------- head: out = r_last @ Wout.T + bout ----------------
    if (tid < BT * 10) {
        int b = tid / 10, o = tid - 10 * (tid / 10);
        float a = bout[o];
        #pragma unroll
        for (int u = 0; u < NH; ++u) a += Wout[o * NH + u] * s_g[(0 * BT + b) * GP + u];
        out[(size_t)(b0 + b) * 10 + o] = a;
    }
}

extern "C" void kernel_launch(void* const* d_in, const int* in_sizes, int n_in,
                              void* d_out, int out_size, void* d_ws, size_t ws_size,
                              hipStream_t stream) {
    const float* x    = (const float*)d_in[0];
    const float* Wih0 = (const float*)d_in[1];
    const float* Whh0 = (const float*)d_in[2];
    const float* bih0 = (const float*)d_in[3];
    const float* bhh0 = (const float*)d_in[4];
    const float* Wih1 = (const float*)d_in[5];
    const float* Whh1 = (const float*)d_in[6];
    const float* bih1 = (const float*)d_in[7];
    const float* bhh1 = (const float*)d_in[8];
    const float* Wout = (const float*)d_in[9];
    const float* bout = (const float*)d_in[10];

    const int B = in_sizes[0] / (NT * NI);      // 2048
    float* out   = (float*)d_out;               // [B,10]
    float* rlast = out + (size_t)B * 10;        // [B,64]

    dim3 grid(B / BT), block(NTH);
    hipLaunchKernelGGL(lstm2_mfma, grid, block, 0, stream,
                       x, Wih0, Whh0, bih0, bhh0, Wih1, Whh1, bih1, bhh1,
                       Wout, bout, out, rlast);
}

// Round 4
// 748.919 us; speedup vs baseline: 11.0870x; 1.2366x over previous
//
#include <hip/hip_runtime.h>
#include <stddef.h>

#define NT 512       // timesteps
#define NI 28        // input dim
#define NH 64        // hidden dim
#define BT 8         // batch rows per block
#define CH 16        // x timesteps per staged chunk
#define XPs 72       // shorts per (t,b) x row: hi[0,32) lo[32,64) pad[64,72) -> 144B
#define HPs 72       // shorts per h row: 64 payload + pad -> 144B
#define NTH 512      // 8 waves: waves 0-3 layer0, 4-7 layer1

typedef short bf16x8 __attribute__((ext_vector_type(8)));
typedef float f32x4  __attribute__((ext_vector_type(4)));

__device__ __forceinline__ short f2bf(float f) {          // fp32 -> bf16 RNE
    unsigned u = __float_as_uint(f);
    u += 0x7FFF + ((u >> 16) & 1);
    return (short)(u >> 16);
}
__device__ __forceinline__ float bf2f(short s) {
    return __uint_as_float(((unsigned)(unsigned short)s) << 16);
}
__device__ __forceinline__ float sigm(float v)  { return __builtin_amdgcn_rcpf(1.f + __expf(-v)); }
__device__ __forceinline__ float tanh_(float v) { return 1.f - 2.f * __builtin_amdgcn_rcpf(__expf(2.f * v) + 1.f); }

// flat x-chunk index [0,896) -> global float4 index
__device__ __forceinline__ size_t gxi(int idx, int n0, int b0) {
    int b   = idx / (CH * 7);
    int rem = idx - b * (CH * 7);
    int t   = rem / 7;
    int w7  = rem - t * 7;
    return ((size_t)(b0 + b) * NT + (n0 + t)) * 7 + w7;
}
// convert float4 -> split bf16 and store into x chunk buffer
__device__ __forceinline__ void xstore(short* dst, int idx, float4 v) {
    int b   = idx / (CH * 7);
    int rem = idx - b * (CH * 7);
    int t   = rem / 7;
    int w7  = rem - t * 7;
    short* row = dst + (t * BT + b) * XPs;
    short h0 = f2bf(v.x), h1 = f2bf(v.y), h2 = f2bf(v.z), h3 = f2bf(v.w);
    short l0 = f2bf(v.x - bf2f(h0)), l1 = f2bf(v.y - bf2f(h1));
    short l2 = f2bf(v.z - bf2f(h2)), l3 = f2bf(v.w - bf2f(h3));
    unsigned hA = (unsigned short)h0 | ((unsigned)(unsigned short)h1 << 16);
    unsigned hB = (unsigned short)h2 | ((unsigned)(unsigned short)h3 << 16);
    unsigned lA = (unsigned short)l0 | ((unsigned)(unsigned short)l1 << 16);
    unsigned lB = (unsigned short)l2 | ((unsigned)(unsigned short)l3 << 16);
    *(uint2*)(row + 4 * w7)      = make_uint2(hA, hB);
    *(uint2*)(row + 32 + 4 * w7) = make_uint2(lA, lB);
}

__global__ __launch_bounds__(NTH, 2)
void lstm2_mfma(const float* __restrict__ x,
                const float* __restrict__ Wih0, const float* __restrict__ Whh0,
                const float* __restrict__ bih0, const float* __restrict__ bhh0,
                const float* __restrict__ Wih1, const float* __restrict__ Whh1,
                const float* __restrict__ bih1, const float* __restrict__ bhh1,
                const float* __restrict__ Wout, const float* __restrict__ bout,
                float* __restrict__ out, float* __restrict__ rlast)
{
    __shared__ __align__(16) short s_x[2][CH * BT * XPs];   // double-buffered x chunks
    __shared__ __align__(16) short s_h[2][2][BT * HPs];     // [layer][parity][b][u] bf16
    __shared__ __align__(16) float s_hf[BT * NH];           // fp32 h1(T-1) for head

    const int tid = threadIdx.x;
    const int ln  = tid & 63;
    const int wv  = tid >> 6;
    const int lay = wv >> 2;          // 0: layer0 waves, 1: layer1 waves
    const int w4  = wv & 3;           // 16-unit slice within the layer
    const int b0  = blockIdx.x * BT;

    const int colB = ln & 15;         // B/D column within tile
    const int kq   = (ln >> 4) * 8;   // k offset of this lane's 8 A/B elements
    const int bA   = ln & 7;          // A batch row (rows 8-15 duplicate 0-7)
    const int ue   = w4 * 16 + colB;  // hidden unit this lane's tiles cover
    const int m0   = (ln >> 4) * 4;   // first batch row in D frag (valid for ln<32)

    // ---------------- B fragments: weights -> split bf16, in registers ----------------
    // tile t = gate type (i,f,g,o); columns = units [16*w4, 16*w4+16)
    // B layout: lane holds B[k=kq+j][n=colB] = W[g][k], g = 64*t + ue
    bf16x8 Bh[4][4], Bl[4][4];
    float  biasf[4];
    #pragma unroll
    for (int t = 0; t < 4; ++t) {
        const int g = 64 * t + ue;
        if (lay == 0) {
            biasf[t] = bih0[g] + bhh0[g];
            #pragma unroll
            for (int j = 0; j < 8; ++j) {
                int k = kq + j;
                float w0 = (k < NI) ? Wih0[g * NI + k] : 0.f;
                short hh = f2bf(w0); Bh[t][0][j] = hh; Bl[t][0][j] = f2bf(w0 - bf2f(hh));
                float w1 = Whh0[g * NH + k];
                hh = f2bf(w1); Bh[t][1][j] = hh; Bl[t][1][j] = f2bf(w1 - bf2f(hh));
                float w2 = Whh0[g * NH + 32 + k];
                hh = f2bf(w2); Bh[t][2][j] = hh; Bl[t][2][j] = f2bf(w2 - bf2f(hh));
                Bh[t][3][j] = 0; Bl[t][3][j] = 0;
            }
        } else {
            biasf[t] = bih1[g] + bhh1[g];
            #pragma unroll
            for (int j = 0; j < 8; ++j) {
                int k = kq + j;
                float w0 = Wih1[g * NH + k];
                short hh = f2bf(w0); Bh[t][0][j] = hh; Bl[t][0][j] = f2bf(w0 - bf2f(hh));
                float w1 = Wih1[g * NH + 32 + k];
                hh = f2bf(w1); Bh[t][1][j] = hh; Bl[t][1][j] = f2bf(w1 - bf2f(hh));
                float w2 = Whh1[g * NH + k];
                hh = f2bf(w2); Bh[t][2][j] = hh; Bl[t][2][j] = f2bf(w2 - bf2f(hh));
                float w3 = Whh1[g * NH + 32 + k];
                hh = f2bf(w3); Bh[t][3][j] = hh; Bl[t][3][j] = f2bf(w3 - bf2f(hh));
            }
        }
    }

    // ---------------- prologue: zero LDS, stage x chunk 0 ----------------
    #pragma unroll 1
    for (int i = tid; i < (int)(sizeof(s_x) / 4); i += NTH) ((int*)s_x)[i] = 0;
    #pragma unroll 1
    for (int i = tid; i < (int)(sizeof(s_h) / 4); i += NTH) ((int*)s_h)[i] = 0;

    const float4* xg4 = (const float4*)x;
    {
        float4 v = xg4[gxi(tid, 0, b0)];
        xstore(s_x[0], tid, v);
        if (tid < 384) {
            float4 v2 = xg4[gxi(tid + NTH, 0, b0)];
            xstore(s_x[0], tid + NTH, v2);
        }
    }
    __syncthreads();

    float cc[4] = {0.f, 0.f, 0.f, 0.f};   // cell state for this lane's 4 cells
    float4 pfA, pfB;                       // x prefetch registers

    // Skewed pipeline: iter n computes gates0(n) [waves 0-3, n<NT] and
    // gates1(n-1) [waves 4-7, n>=1]; EW in registers; 1 barrier per iter.
    // h(m) written into parity m&1; read h0(n-1)@(n-1)&1, h1(n-2)@n&1.
    for (int n = 0; n <= NT; ++n) {
        const int k16 = n >> 4;
        if ((n & 15) == 0 && n + CH < NT) {           // issue x prefetch
            pfA = xg4[gxi(tid, n + CH, b0)];
            if (tid < 384) pfB = xg4[gxi(tid + NTH, n + CH, b0)];
        }

        const int p1 = (n - 1) & 1;
        if (lay == 0) {
            if (n < NT) {
                const short* xrow = s_x[k16 & 1] + ((n & 15) * BT + bA) * XPs;
                bf16x8 Ahx = *(const bf16x8*)(xrow + kq);
                bf16x8 Alx = *(const bf16x8*)(xrow + 32 + kq);
                const short* h0r = s_h[0][p1] + bA * HPs;
                bf16x8 A0 = *(const bf16x8*)(h0r + kq);
                bf16x8 A1 = *(const bf16x8*)(h0r + 32 + kq);
                f32x4 acc[4];
                #pragma unroll
                for (int t = 0; t < 4; ++t) {
                    f32x4 a = { biasf[t], biasf[t], biasf[t], biasf[t] };
                    a = __builtin_amdgcn_mfma_f32_16x16x32_bf16(Ahx, Bh[t][0], a, 0, 0, 0);
                    a = __builtin_amdgcn_mfma_f32_16x16x32_bf16(Alx, Bh[t][0], a, 0, 0, 0);
                    a = __builtin_amdgcn_mfma_f32_16x16x32_bf16(Ahx, Bl[t][0], a, 0, 0, 0);
                    a = __builtin_amdgcn_mfma_f32_16x16x32_bf16(A0,  Bh[t][1], a, 0, 0, 0);
                    a = __builtin_amdgcn_mfma_f32_16x16x32_bf16(A0,  Bl[t][1], a, 0, 0, 0);
                    a = __builtin_amdgcn_mfma_f32_16x16x32_bf16(A1,  Bh[t][2], a, 0, 0, 0);
                    a = __builtin_amdgcn_mfma_f32_16x16x32_bf16(A1,  Bl[t][2], a, 0, 0, 0);
                    acc[t] = a;
                }
                if (ln < 32) {                        // in-register elementwise, h0(n)
                    short* hw = s_h[0][n & 1];
                    #pragma unroll
                    for (int r = 0; r < 4; ++r) {
                        float ii = sigm(acc[0][r]), ff = sigm(acc[1][r]);
                        float gg = tanh_(acc[2][r]), oo = sigm(acc[3][r]);
                        cc[r] = ff * cc[r] + ii * gg;
                        float h = oo * tanh_(cc[r]);
                        hw[(m0 + r) * HPs + ue] = f2bf(h);
                    }
                }
            }
        } else {
            if (n >= 1) {
                const int p2 = n & 1;                 // h1(n-2) parity
                const short* h0r = s_h[0][p1] + bA * HPs;
                const short* h1r = s_h[1][p2] + bA * HPs;
                bf16x8 A0 = *(const bf16x8*)(h0r + kq);
                bf16x8 A1 = *(const bf16x8*)(h0r + 32 + kq);
                bf16x8 A2 = *(const bf16x8*)(h1r + kq);
                bf16x8 A3 = *(const bf16x8*)(h1r + 32 + kq);
                f32x4 acc[4];
                #pragma unroll
                for (int t = 0; t < 4; ++t) {
                    f32x4 a = { biasf[t], biasf[t], biasf[t], biasf[t] };
                    a = __builtin_amdgcn_mfma_f32_16x16x32_bf16(A0, Bh[t][0], a, 0, 0, 0);
                    a = __builtin_amdgcn_mfma_f32_16x16x32_bf16(A0, Bl[t][0], a, 0, 0, 0);
                    a = __builtin_amdgcn_mfma_f32_16x16x32_bf16(A1, Bh[t][1], a, 0, 0, 0);
                    a = __builtin_amdgcn_mfma_f32_16x16x32_bf16(A1, Bl[t][1], a, 0, 0, 0);
                    a = __builtin_amdgcn_mfma_f32_16x16x32_bf16(A2, Bh[t][2], a, 0, 0, 0);
                    a = __builtin_amdgcn_mfma_f32_16x16x32_bf16(A2, Bl[t][2], a, 0, 0, 0);
                    a = __builtin_amdgcn_mfma_f32_16x16x32_bf16(A3, Bh[t][3], a, 0, 0, 0);
                    a = __builtin_amdgcn_mfma_f32_16x16x32_bf16(A3, Bl[t][3], a, 0, 0, 0);
                    acc[t] = a;
                }
                if (ln < 32) {                        // elementwise, h1(n-1)
                    short* hw = s_h[1][(n - 1) & 1];
                    #pragma unroll
                    for (int r = 0; r < 4; ++r) {
                        float ii = sigm(acc[0][r]), ff = sigm(acc[1][r]);
                        float gg = tanh_(acc[2][r]), oo = sigm(acc[3][r]);
                        cc[r] = ff * cc[r] + ii * gg;
                        float h = oo * tanh_(cc[r]);
                        hw[(m0 + r) * HPs + ue] = f2bf(h);
                        if (n == NT) {
                            rlast[(size_t)(b0 + m0 + r) * NH + ue] = h;
                            s_hf[(m0 + r) * NH + ue] = h;
                        }
                    }
                }
            }
        }

        if ((n & 15) == 15 && n + 1 < NT) {           // convert prefetched chunk
            short* dst = s_x[(k16 + 1) & 1];
            xstore(dst, tid, pfA);
            if (tid < 384) xstore(dst, tid + NTH, pfB);
        }
        __syncthreads();
    }

    // ---------------- head: out = r_last @ Wout.T + bout ----------------
    if (tid < BT * 10) {
        int b = tid / 10, o = tid - 10 * (tid / 10);
        float a = bout[o];
        #pragma unroll
        for (int u = 0; u < NH; ++u) a += Wout[o * NH + u] * s_hf[b * NH + u];
        out[(size_t)(b0 + b) * 10 + o] = a;
    }
}

extern "C" void kernel_launch(void* const* d_in, const int* in_sizes, int n_in,
                              void* d_out, int out_size, void* d_ws, size_t ws_size,
                              hipStream_t stream) {
    const float* x    = (const float*)d_in[0];
    const float* Wih0 = (const float*)d_in[1];
    const float* Whh0 = (const float*)d_in[2];
    const float* bih0 = (const float*)d_in[3];
    const float* bhh0 = (const float*)d_in[4];
    const float* Wih1 = (const float*)d_in[5];
    const float* Whh1 = (const float*)d_in[6];
    const float* bih1 = (const float*)d_in[7];
    const float* bhh1 = (const float*)d_in[8];
    const float* Wout = (const float*)d_in[9];
    const float* bout = (const float*)d_in[10];

    const int B = in_sizes[0] / (NT * NI);      // 2048
    float* out   = (float*)d_out;               // [B,10]
    float* rlast = out + (size_t)B * 10;        // [B,64]

    dim3 grid(B / BT), block(NTH);
    hipLaunchKernelGGL(lstm2_mfma, grid, block, 0, stream,
                       x, Wih0, Whh0, bih0, bhh0, Wih1, Whh1, bih1, bhh1,
                       Wout, bout, out, rlast);
}

// Round 5
// 610.603 us; speedup vs baseline: 13.5984x; 1.2265x over previous
//
#include <hip/hip_runtime.h>
#include <stddef.h>

#define NT 512       // timesteps
#define NI 28        // input dim
#define NH 64        // hidden dim
#define BT 8         // batch rows per block
#define CH 16        // x timesteps per staged chunk
#define XPs 72       // shorts per (t,b) x row: hi[0,32) lo[32,64) pad -> 144B
#define HPs 72       // shorts per h row: 64 payload + 8 pad -> 144B
#define NTH 512      // 8 waves: 0-3 layer0, 4-7 layer1

typedef short bf16x8 __attribute__((ext_vector_type(8)));
typedef float f32x4  __attribute__((ext_vector_type(4)));

__device__ __forceinline__ short f2bf(float f) {          // fp32 -> bf16 RNE
    unsigned u = __float_as_uint(f);
    u += 0x7FFF + ((u >> 16) & 1);
    return (short)(u >> 16);
}
__device__ __forceinline__ float bf2f(short s) {
    return __uint_as_float(((unsigned)(unsigned short)s) << 16);
}
__device__ __forceinline__ float sigm(float v)  { return __builtin_amdgcn_rcpf(1.f + __expf(-v)); }
__device__ __forceinline__ float tanh_(float v) { return 1.f - 2.f * __builtin_amdgcn_rcpf(__expf(2.f * v) + 1.f); }

// flat x-chunk index [0,896) -> global float4 index
__device__ __forceinline__ size_t gxi(int idx, int n0, int b0) {
    int b   = idx / (CH * 7);
    int rem = idx - b * (CH * 7);
    int t   = rem / 7;
    int w7  = rem - t * 7;
    return ((size_t)(b0 + b) * NT + (n0 + t)) * 7 + w7;
}
// convert float4 -> split bf16, store into x chunk buffer
__device__ __forceinline__ void xstore(short* dst, int idx, float4 v) {
    int b   = idx / (CH * 7);
    int rem = idx - b * (CH * 7);
    int t   = rem / 7;
    int w7  = rem - t * 7;
    short* row = dst + (t * BT + b) * XPs;
    short h0 = f2bf(v.x), h1 = f2bf(v.y), h2 = f2bf(v.z), h3 = f2bf(v.w);
    short l0 = f2bf(v.x - bf2f(h0)), l1 = f2bf(v.y - bf2f(h1));
    short l2 = f2bf(v.z - bf2f(h2)), l3 = f2bf(v.w - bf2f(h3));
    unsigned hA = (unsigned short)h0 | ((unsigned)(unsigned short)h1 << 16);
    unsigned hB = (unsigned short)h2 | ((unsigned)(unsigned short)h3 << 16);
    unsigned lA = (unsigned short)l0 | ((unsigned)(unsigned short)l1 << 16);
    unsigned lB = (unsigned short)l2 | ((unsigned)(unsigned short)l3 << 16);
    *(uint2*)(row + 4 * w7)      = make_uint2(hA, hB);
    *(uint2*)(row + 32 + 4 * w7) = make_uint2(lA, lB);
}

__global__ __launch_bounds__(NTH, 2)
void lstm2_mfma(const float* __restrict__ x,
                const float* __restrict__ Wih0, const float* __restrict__ Whh0,
                const float* __restrict__ bih0, const float* __restrict__ bhh0,
                const float* __restrict__ Wih1, const float* __restrict__ Whh1,
                const float* __restrict__ bih1, const float* __restrict__ bhh1,
                const float* __restrict__ Wout, const float* __restrict__ bout,
                float* __restrict__ out, float* __restrict__ rlast)
{
    __shared__ __align__(16) short s_x[2][CH * BT * XPs];   // double-buffered x
    __shared__ __align__(16) short s_h0[2][BT * HPs];       // h0 parity buffers
    __shared__ __align__(16) short s_h1[2][BT * HPs];       // h1 parity buffers
    __shared__ __align__(16) float s_hf[BT * NH];           // fp32 h1(T-1) for head

    const int tid = threadIdx.x;
    const int ln  = tid & 63;
    const int wv  = tid >> 6;
    const int lay = wv >> 2;          // 0: layer0 waves, 1: layer1 waves
    const int w4  = wv & 3;           // 16-unit slice within the layer
    const int b0  = blockIdx.x * BT;

    const int colB = ln & 15;         // B/D column within tile
    const int kq   = (ln >> 4) * 8;   // k offset of this lane's 8 A/B elements
    const int bA   = ln & 7;          // A batch row (rows 8-15 duplicate 0-7)
    const int ue   = w4 * 16 + colB;  // hidden unit of this lane's tile column
    const int m0   = (ln >> 4) * 4;   // first D row of this lane's fragment
    const int rq   = (ln >= 32) ? 2 : 0;        // which acc pair this lane handles
    const int bm0  = (m0 + rq) & 7;             // batch of cell 0
    const int bm1  = (m0 + rq + 1) & 7;         // batch of cell 1
    const bool hi  = (rq != 0);
    const int off0 = bm0 * HPs + ue;            // h write offsets
    const int off1 = bm1 * HPs + ue;

    // ---------------- prologue: zero LDS, stage x chunk 0 ----------------
    #pragma unroll 1
    for (int i = tid; i < (int)(sizeof(s_x) / 4); i += NTH) ((int*)s_x)[i] = 0;
    #pragma unroll 1
    for (int i = tid; i < (int)((sizeof(s_h0) + sizeof(s_h1)) / 4); i += NTH) ((int*)s_h0)[i] = 0;

    const float4* xg4 = (const float4*)x;
    {
        float4 v = xg4[gxi(tid, 0, b0)];
        xstore(s_x[0], tid, v);
        if (tid < 384) {
            float4 v2 = xg4[gxi(tid + NTH, 0, b0)];
            xstore(s_x[0], tid + NTH, v2);
        }
    }
    __syncthreads();

    const f32x4 z4 = { 0.f, 0.f, 0.f, 0.f };
    float cc0 = 0.f, cc1 = 0.f;        // this lane's 2 cell states
    float4 pfA, pfB;                   // x prefetch registers

    if (lay == 0) {
        // ---- B fragments, layer0: chunks {x, h0[0:32), h0[32:64)} ----
        bf16x8 Bh[4][3], Bl[4][3]; float biasf[4];
        #pragma unroll
        for (int t = 0; t < 4; ++t) {
            const int g = 64 * t + ue;
            biasf[t] = bih0[g] + bhh0[g];
            #pragma unroll
            for (int j = 0; j < 8; ++j) {
                int k = kq + j;
                float w0 = (k < NI) ? Wih0[g * NI + k] : 0.f;
                short hh = f2bf(w0); Bh[t][0][j] = hh; Bl[t][0][j] = f2bf(w0 - bf2f(hh));
                float w1 = Whh0[g * NH + k];
                hh = f2bf(w1); Bh[t][1][j] = hh; Bl[t][1][j] = f2bf(w1 - bf2f(hh));
                float w2 = Whh0[g * NH + 32 + k];
                hh = f2bf(w2); Bh[t][2][j] = hh; Bl[t][2][j] = f2bf(w2 - bf2f(hh));
            }
        }
        #pragma unroll 1
        for (int n = 0; n <= NT; ++n) {
            if ((n & 15) == 0 && n + CH < NT) {
                pfA = xg4[gxi(tid, n + CH, b0)];
                if (tid < 384) pfB = xg4[gxi(tid + NTH, n + CH, b0)];
            }
            if (n < NT) {
                const short* xrow = s_x[(n >> 4) & 1] + ((n & 15) * BT + bA) * XPs;
                bf16x8 Ahx = *(const bf16x8*)(xrow + kq);
                bf16x8 Alx = *(const bf16x8*)(xrow + 32 + kq);
                const short* h0r = s_h0[(n - 1) & 1] + bA * HPs;
                bf16x8 A0 = *(const bf16x8*)(h0r + kq);
                bf16x8 A1 = *(const bf16x8*)(h0r + 32 + kq);
                f32x4 acc[4];
                #pragma unroll
                for (int t = 0; t < 4; ++t) {
                    f32x4 a;
                    a = __builtin_amdgcn_mfma_f32_16x16x32_bf16(Ahx, Bh[t][0], z4, 0, 0, 0);
                    a = __builtin_amdgcn_mfma_f32_16x16x32_bf16(Alx, Bh[t][0], a, 0, 0, 0);
                    a = __builtin_amdgcn_mfma_f32_16x16x32_bf16(Ahx, Bl[t][0], a, 0, 0, 0);
                    a = __builtin_amdgcn_mfma_f32_16x16x32_bf16(A0,  Bh[t][1], a, 0, 0, 0);
                    a = __builtin_amdgcn_mfma_f32_16x16x32_bf16(A0,  Bl[t][1], a, 0, 0, 0);
                    a = __builtin_amdgcn_mfma_f32_16x16x32_bf16(A1,  Bh[t][2], a, 0, 0, 0);
                    a = __builtin_amdgcn_mfma_f32_16x16x32_bf16(A1,  Bl[t][2], a, 0, 0, 0);
                    acc[t] = a;
                }
                // all-lane EW: lanes<32 use acc[.][0,1], lanes>=32 acc[.][2,3]
                float g00 = (hi ? acc[0][2] : acc[0][0]) + biasf[0];
                float g10 = (hi ? acc[1][2] : acc[1][0]) + biasf[1];
                float g20 = (hi ? acc[2][2] : acc[2][0]) + biasf[2];
                float g30 = (hi ? acc[3][2] : acc[3][0]) + biasf[3];
                float g01 = (hi ? acc[0][3] : acc[0][1]) + biasf[0];
                float g11 = (hi ? acc[1][3] : acc[1][1]) + biasf[1];
                float g21 = (hi ? acc[2][3] : acc[2][1]) + biasf[2];
                float g31 = (hi ? acc[3][3] : acc[3][1]) + biasf[3];
                short* hw = s_h0[n & 1];
                cc0 = sigm(g10) * cc0 + sigm(g00) * tanh_(g20);
                hw[off0] = f2bf(sigm(g30) * tanh_(cc0));
                cc1 = sigm(g11) * cc1 + sigm(g01) * tanh_(g21);
                hw[off1] = f2bf(sigm(g31) * tanh_(cc1));
            }
            if ((n & 15) == 15 && n + 1 < NT) {
                short* dst = s_x[((n >> 4) + 1) & 1];
                xstore(dst, tid, pfA);
                if (tid < 384) xstore(dst, tid + NTH, pfB);
            }
            __syncthreads();
        }
    } else {
        // ---- B fragments, layer1: chunks {h0[0:32), h0[32:64), h1[0:32), h1[32:64)} ----
        bf16x8 Bh[4][4], Bl[4][4]; float biasf[4];
        #pragma unroll
        for (int t = 0; t < 4; ++t) {
            const int g = 64 * t + ue;
            biasf[t] = bih1[g] + bhh1[g];
            #pragma unroll
            for (int j = 0; j < 8; ++j) {
                int k = kq + j;
                float w0 = Wih1[g * NH + k];
                short hh = f2bf(w0); Bh[t][0][j] = hh; Bl[t][0][j] = f2bf(w0 - bf2f(hh));
                float w1 = Wih1[g * NH + 32 + k];
                hh = f2bf(w1); Bh[t][1][j] = hh; Bl[t][1][j] = f2bf(w1 - bf2f(hh));
                float w2 = Whh1[g * NH + k];
                hh = f2bf(w2); Bh[t][2][j] = hh; Bl[t][2][j] = f2bf(w2 - bf2f(hh));
                float w3 = Whh1[g * NH + 32 + k];
                hh = f2bf(w3); Bh[t][3][j] = hh; Bl[t][3][j] = f2bf(w3 - bf2f(hh));
            }
        }
        #pragma unroll 1
        for (int n = 0; n <= NT; ++n) {
            if ((n & 15) == 0 && n + CH < NT) {
                pfA = xg4[gxi(tid, n + CH, b0)];
                if (tid < 384) pfB = xg4[gxi(tid + NTH, n + CH, b0)];
            }
            if (n >= 1) {
                const short* h0r = s_h0[(n - 1) & 1] + bA * HPs;   // h0(n-1)
                const short* h1r = s_h1[n & 1] + bA * HPs;         // h1(n-2)
                bf16x8 A0 = *(const bf16x8*)(h0r + kq);
                bf16x8 A1 = *(const bf16x8*)(h0r + 32 + kq);
                bf16x8 A2 = *(const bf16x8*)(h1r + kq);
                bf16x8 A3 = *(const bf16x8*)(h1r + 32 + kq);
                f32x4 acc[4];
                #pragma unroll
                for (int t = 0; t < 4; ++t) {
                    f32x4 a;
                    a = __builtin_amdgcn_mfma_f32_16x16x32_bf16(A0, Bh[t][0], z4, 0, 0, 0);
                    a = __builtin_amdgcn_mfma_f32_16x16x32_bf16(A0, Bl[t][0], a, 0, 0, 0);
                    a = __builtin_amdgcn_mfma_f32_16x16x32_bf16(A1, Bh[t][1], a, 0, 0, 0);
                    a = __builtin_amdgcn_mfma_f32_16x16x32_bf16(A1, Bl[t][1], a, 0, 0, 0);
                    a = __builtin_amdgcn_mfma_f32_16x16x32_bf16(A2, Bh[t][2], a, 0, 0, 0);
                    a = __builtin_amdgcn_mfma_f32_16x16x32_bf16(A2, Bl[t][2], a, 0, 0, 0);
                    a = __builtin_amdgcn_mfma_f32_16x16x32_bf16(A3, Bh[t][3], a, 0, 0, 0);
                    a = __builtin_amdgcn_mfma_f32_16x16x32_bf16(A3, Bl[t][3], a, 0, 0, 0);
                    acc[t] = a;
                }
                float g00 = (hi ? acc[0][2] : acc[0][0]) + biasf[0];
                float g10 = (hi ? acc[1][2] : acc[1][0]) + biasf[1];
                float g20 = (hi ? acc[2][2] : acc[2][0]) + biasf[2];
                float g30 = (hi ? acc[3][2] : acc[3][0]) + biasf[3];
                float g01 = (hi ? acc[0][3] : acc[0][1]) + biasf[0];
                float g11 = (hi ? acc[1][3] : acc[1][1]) + biasf[1];
                float g21 = (hi ? acc[2][3] : acc[2][1]) + biasf[2];
                float g31 = (hi ? acc[3][3] : acc[3][1]) + biasf[3];
                short* hw = s_h1[(n - 1) & 1];
                cc0 = sigm(g10) * cc0 + sigm(g00) * tanh_(g20);
                float h0v = sigm(g30) * tanh_(cc0);
                hw[off0] = f2bf(h0v);
                cc1 = sigm(g11) * cc1 + sigm(g01) * tanh_(g21);
                float h1v = sigm(g31) * tanh_(cc1);
                hw[off1] = f2bf(h1v);
                if (n == NT) {
                    rlast[(size_t)(b0 + bm0) * NH + ue] = h0v;
                    rlast[(size_t)(b0 + bm1) * NH + ue] = h1v;
                    s_hf[bm0 * NH + ue] = h0v;
                    s_hf[bm1 * NH + ue] = h1v;
                }
            }
            if ((n & 15) == 15 && n + 1 < NT) {
                short* dst = s_x[((n >> 4) + 1) & 1];
                xstore(dst, tid, pfA);
                if (tid < 384) xstore(dst, tid + NTH, pfB);
            }
            __syncthreads();
        }
    }

    // ---------------- head: out = r_last @ Wout.T + bout ----------------
    if (tid < BT * 10) {
        int b = tid / 10, o = tid - 10 * (tid / 10);
        float a = bout[o];
        #pragma unroll
        for (int u = 0; u < NH; ++u) a += Wout[o * NH + u] * s_hf[b * NH + u];
        out[(size_t)(b0 + b) * 10 + o] = a;
    }
}

extern "C" void kernel_launch(void* const* d_in, const int* in_sizes, int n_in,
                              void* d_out, int out_size, void* d_ws, size_t ws_size,
                              hipStream_t stream) {
    const float* x    = (const float*)d_in[0];
    const float* Wih0 = (const float*)d_in[1];
    const float* Whh0 = (const float*)d_in[2];
    const float* bih0 = (const float*)d_in[3];
    const float* bhh0 = (const float*)d_in[4];
    const float* Wih1 = (const float*)d_in[5];
    const float* Whh1 = (const float*)d_in[6];
    const float* bih1 = (const float*)d_in[7];
    const float* bhh1 = (const float*)d_in[8];
    const float* Wout = (const float*)d_in[9];
    const float* bout = (const float*)d_in[10];

    const int B = in_sizes[0] / (NT * NI);      // 2048
    float* out   = (float*)d_out;               // [B,10]
    float* rlast = out + (size_t)B * 10;        // [B,64]

    dim3 grid(B / BT), block(NTH);
    hipLaunchKernelGGL(lstm2_mfma, grid, block, 0, stream,
                       x, Wih0, Whh0, bih0, bhh0, Wih1, Whh1, bih1, bhh1,
                       Wout, bout, out, rlast);
}

// Round 6
// 494.703 us; speedup vs baseline: 16.7843x; 1.2343x over previous
//
#include <hip/hip_runtime.h>
#include <stddef.h>

#define NT 512       // timesteps
#define NI 28        // input dim
#define NH 64        // hidden dim
#define BT 8         // batch rows per block
#define CH 16        // x timesteps per staged chunk
#define XPh 36       // halfs per (t,b) x row: 28 payload + pad(28..35); pad[28]=1.0 (bias col)
#define HPh 72       // halfs per h row: 64 payload + 8 pad -> 144B (36-dw bank stride)
#define NTH 512      // 8 waves: 0-3 layer0, 4-7 layer1

typedef _Float16 f16x8 __attribute__((ext_vector_type(8)));
typedef float    f32x4 __attribute__((ext_vector_type(4)));

__device__ __forceinline__ float sigm(float v)  { return __builtin_amdgcn_rcpf(1.f + __expf(-v)); }
__device__ __forceinline__ float tanh_(float v) { return 1.f - 2.f * __builtin_amdgcn_rcpf(__expf(2.f * v) + 1.f); }

// flat x-chunk index [0,896) -> global float4 index
__device__ __forceinline__ size_t gxi(int idx, int n0, int b0) {
    int b   = idx / (CH * 7);
    int rem = idx - b * (CH * 7);
    int t   = rem / 7;
    int w7  = rem - t * 7;
    return ((size_t)(b0 + b) * NT + (n0 + t)) * 7 + w7;
}
// convert float4 -> f16x4, store into x chunk buffer
__device__ __forceinline__ void xstoreh(_Float16* dst, int idx, float4 v) {
    int b   = idx / (CH * 7);
    int rem = idx - b * (CH * 7);
    int t   = rem / 7;
    int w7  = rem - t * 7;
    _Float16* row = dst + (t * BT + b) * XPh;
    _Float16 tmp[4] = { (_Float16)v.x, (_Float16)v.y, (_Float16)v.z, (_Float16)v.w };
    *(uint2*)(row + 4 * w7) = *(const uint2*)tmp;
}

__global__ __launch_bounds__(NTH, 2)
void lstm2_mfma(const float* __restrict__ x,
                const float* __restrict__ Wih0, const float* __restrict__ Whh0,
                const float* __restrict__ bih0, const float* __restrict__ bhh0,
                const float* __restrict__ Wih1, const float* __restrict__ Whh1,
                const float* __restrict__ bih1, const float* __restrict__ bhh1,
                const float* __restrict__ Wout, const float* __restrict__ bout,
                float* __restrict__ out, float* __restrict__ rlast)
{
    __shared__ __align__(16) _Float16 s_x[2][CH * BT * XPh];  // double-buffered x (f16)
    __shared__ __align__(16) _Float16 s_h0[2][BT * HPh];      // h0 parity buffers
    __shared__ __align__(16) _Float16 s_h1[2][BT * HPh];      // h1 parity buffers
    __shared__ __align__(16) float    s_hf[BT * NH];          // fp32 h1(T-1) for head

    const int tid = threadIdx.x;
    const int ln  = tid & 63;
    const int wv  = tid >> 6;
    const int lay = wv >> 2;          // 0: layer0 waves, 1: layer1 waves
    const int w4  = wv & 3;           // 16-unit slice within the layer
    const int b0  = blockIdx.x * BT;

    const int colB = ln & 15;         // B/D column within tile
    const int kq   = (ln >> 4) * 8;   // k offset of this lane's 8 A/B elements
    const int bA   = ln & 7;          // A batch row (rows 8-15 duplicate 0-7)
    const int ue   = w4 * 16 + colB;  // hidden unit of this lane's tile column
    const int m0   = (ln >> 4) * 4;   // first D row of this lane's fragment
    const int rq   = (ln >= 32) ? 2 : 0;        // acc pair handled by this lane
    const int bm0  = (m0 + rq) & 7;             // batch of cell 0
    const int bm1  = (m0 + rq + 1) & 7;         // batch of cell 1
    const bool hi  = (rq != 0);
    const int off0 = bm0 * HPh + ue;            // h write offsets
    const int off1 = bm1 * HPh + ue;

    // ---------------- prologue: zero LDS, bias column, stage x chunk 0 ----------------
    #pragma unroll 1
    for (int i = tid; i < (int)(sizeof(s_x) / 4); i += NTH) ((int*)s_x)[i] = 0;
    #pragma unroll 1
    for (int i = tid; i < (int)((sizeof(s_h0) + sizeof(s_h1)) / 4); i += NTH) ((int*)s_h0)[i] = 0;
    __syncthreads();                       // zeroing visible before pad-col writes
    if (tid < 2 * CH * BT) {               // set x pad column k=28 to 1.0 (bias input)
        int buf = tid >> 7, r = tid & 127;
        s_x[buf][r * XPh + 28] = (_Float16)1.0f;
    }

    const float4* xg4 = (const float4*)x;
    {
        float4 v = xg4[gxi(tid, 0, b0)];
        xstoreh(s_x[0], tid, v);
        if (tid < 384) {
            float4 v2 = xg4[gxi(tid + NTH, 0, b0)];
            xstoreh(s_x[0], tid + NTH, v2);
        }
    }
    __syncthreads();

    const f32x4 z4 = { 0.f, 0.f, 0.f, 0.f };
    float cc0 = 0.f, cc1 = 0.f;        // this lane's 2 cell states
    float4 pfA, pfB;                   // x prefetch registers

    if (lay == 0) {
        // ---- B fragments, layer0 (f16): chunks {x(+bias col), h0[0:32), h0[32:64)} ----
        f16x8 B0[4], B1[4], B2[4];
        #pragma unroll
        for (int t = 0; t < 4; ++t) {
            const int g = 64 * t + ue;
            const float bias0 = bih0[g] + bhh0[g];
            #pragma unroll
            for (int j = 0; j < 8; ++j) {
                int k = kq + j;
                float w0 = (k < NI) ? Wih0[g * NI + k] : (k == 28 ? bias0 : 0.f);
                B0[t][j] = (_Float16)w0;
                B1[t][j] = (_Float16)Whh0[g * NH + k];
                B2[t][j] = (_Float16)Whh0[g * NH + 32 + k];
            }
        }
        #pragma unroll 1
        for (int n = 0; n <= NT; ++n) {
            if ((n & 15) == 0 && n + CH < NT) {
                pfA = xg4[gxi(tid, n + CH, b0)];
                if (tid < 384) pfB = xg4[gxi(tid + NTH, n + CH, b0)];
            }
            if (n < NT) {
                const _Float16* xrow = s_x[(n >> 4) & 1] + ((n & 15) * BT + bA) * XPh;
                f16x8 Ax = *(const f16x8*)(xrow + kq);
                const _Float16* h0r = s_h0[(n - 1) & 1] + bA * HPh;
                f16x8 A0 = *(const f16x8*)(h0r + kq);
                f16x8 A1 = *(const f16x8*)(h0r + 32 + kq);
                f32x4 acc[4];
                #pragma unroll
                for (int t = 0; t < 4; ++t) {
                    f32x4 a;
                    a = __builtin_amdgcn_mfma_f32_16x16x32_f16(Ax, B0[t], z4, 0, 0, 0);
                    a = __builtin_amdgcn_mfma_f32_16x16x32_f16(A0, B1[t], a, 0, 0, 0);
                    a = __builtin_amdgcn_mfma_f32_16x16x32_f16(A1, B2[t], a, 0, 0, 0);
                    acc[t] = a;
                }
                // all-lane EW (bias already in via x pad column)
                float g00 = hi ? acc[0][2] : acc[0][0];
                float g10 = hi ? acc[1][2] : acc[1][0];
                float g20 = hi ? acc[2][2] : acc[2][0];
                float g30 = hi ? acc[3][2] : acc[3][0];
                float g01 = hi ? acc[0][3] : acc[0][1];
                float g11 = hi ? acc[1][3] : acc[1][1];
                float g21 = hi ? acc[2][3] : acc[2][1];
                float g31 = hi ? acc[3][3] : acc[3][1];
                _Float16* hw = s_h0[n & 1];
                cc0 = sigm(g10) * cc0 + sigm(g00) * tanh_(g20);
                hw[off0] = (_Float16)(sigm(g30) * tanh_(cc0));
                cc1 = sigm(g11) * cc1 + sigm(g01) * tanh_(g21);
                hw[off1] = (_Float16)(sigm(g31) * tanh_(cc1));
            }
            if ((n & 15) == 15 && n + 1 < NT) {
                _Float16* dst = s_x[((n >> 4) + 1) & 1];
                xstoreh(dst, tid, pfA);
                if (tid < 384) xstoreh(dst, tid + NTH, pfB);
            }
            __syncthreads();
        }
    } else {
        // ---- B fragments, layer1 (f16): chunks {h0[0:32), h0[32:64), h1[0:32), h1[32:64)} ----
        f16x8 B0[4], B1[4], B2[4], B3[4]; float biasf[4];
        #pragma unroll
        for (int t = 0; t < 4; ++t) {
            const int g = 64 * t + ue;
            biasf[t] = bih1[g] + bhh1[g];
            #pragma unroll
            for (int j = 0; j < 8; ++j) {
                int k = kq + j;
                B0[t][j] = (_Float16)Wih1[g * NH + k];
                B1[t][j] = (_Float16)Wih1[g * NH + 32 + k];
                B2[t][j] = (_Float16)Whh1[g * NH + k];
                B3[t][j] = (_Float16)Whh1[g * NH + 32 + k];
            }
        }
        #pragma unroll 1
        for (int n = 0; n <= NT; ++n) {
            if ((n & 15) == 0 && n + CH < NT) {
                pfA = xg4[gxi(tid, n + CH, b0)];
                if (tid < 384) pfB = xg4[gxi(tid + NTH, n + CH, b0)];
            }
            if (n >= 1) {
                const _Float16* h0r = s_h0[(n - 1) & 1] + bA * HPh;   // h0(n-1)
                const _Float16* h1r = s_h1[n & 1] + bA * HPh;         // h1(n-2)
                f16x8 A0 = *(const f16x8*)(h0r + kq);
                f16x8 A1 = *(const f16x8*)(h0r + 32 + kq);
                f16x8 A2 = *(const f16x8*)(h1r + kq);
                f16x8 A3 = *(const f16x8*)(h1r + 32 + kq);
                f32x4 acc[4];
                #pragma unroll
                for (int t = 0; t < 4; ++t) {
                    f32x4 a;
                    a = __builtin_amdgcn_mfma_f32_16x16x32_f16(A0, B0[t], z4, 0, 0, 0);
                    a = __builtin_amdgcn_mfma_f32_16x16x32_f16(A1, B1[t], a, 0, 0, 0);
                    a = __builtin_amdgcn_mfma_f32_16x16x32_f16(A2, B2[t], a, 0, 0, 0);
                    a = __builtin_amdgcn_mfma_f32_16x16x32_f16(A3, B3[t], a, 0, 0, 0);
                    acc[t] = a;
                }
                float g00 = (hi ? acc[0][2] : acc[0][0]) + biasf[0];
                float g10 = (hi ? acc[1][2] : acc[1][0]) + biasf[1];
                float g20 = (hi ? acc[2][2] : acc[2][0]) + biasf[2];
                float g30 = (hi ? acc[3][2] : acc[3][0]) + biasf[3];
                float g01 = (hi ? acc[0][3] : acc[0][1]) + biasf[0];
                float g11 = (hi ? acc[1][3] : acc[1][1]) + biasf[1];
                float g21 = (hi ? acc[2][3] : acc[2][1]) + biasf[2];
                float g31 = (hi ? acc[3][3] : acc[3][1]) + biasf[3];
                _Float16* hw = s_h1[(n - 1) & 1];
                cc0 = sigm(g10) * cc0 + sigm(g00) * tanh_(g20);
                float h0v = sigm(g30) * tanh_(cc0);
                hw[off0] = (_Float16)h0v;
                cc1 = sigm(g11) * cc1 + sigm(g01) * tanh_(g21);
                float h1v = sigm(g31) * tanh_(cc1);
                hw[off1] = (_Float16)h1v;
                if (n == NT) {
                    rlast[(size_t)(b0 + bm0) * NH + ue] = h0v;
                    rlast[(size_t)(b0 + bm1) * NH + ue] = h1v;
                    s_hf[bm0 * NH + ue] = h0v;
                    s_hf[bm1 * NH + ue] = h1v;
                }
            }
            if ((n & 15) == 15 && n + 1 < NT) {
                _Float16* dst = s_x[((n >> 4) + 1) & 1];
                xstoreh(dst, tid, pfA);
                if (tid < 384) xstoreh(dst, tid + NTH, pfB);
            }
            __syncthreads();
        }
    }

    // ---------------- head: out = r_last @ Wout.T + bout ----------------
    if (tid < BT * 10) {
        int b = tid / 10, o = tid - 10 * (tid / 10);
        float a = bout[o];
        #pragma unroll
        for (int u = 0; u < NH; ++u) a += Wout[o * NH + u] * s_hf[b * NH + u];
        out[(size_t)(b0 + b) * 10 + o] = a;
    }
}

extern "C" void kernel_launch(void* const* d_in, const int* in_sizes, int n_in,
                              void* d_out, int out_size, void* d_ws, size_t ws_size,
                              hipStream_t stream) {
    const float* x    = (const float*)d_in[0];
    const float* Wih0 = (const float*)d_in[1];
    const float* Whh0 = (const float*)d_in[2];
    const float* bih0 = (const float*)d_in[3];
    const float* bhh0 = (const float*)d_in[4];
    const float* Wih1 = (const float*)d_in[5];
    const float* Whh1 = (const float*)d_in[6];
    const float* bih1 = (const float*)d_in[7];
    const float* bhh1 = (const float*)d_in[8];
    const float* Wout = (const float*)d_in[9];
    const float* bout = (const float*)d_in[10];

    const int B = in_sizes[0] / (NT * NI);      // 2048
    float* out   = (float*)d_out;               // [B,10]
    float* rlast = out + (size_t)B * 10;        // [B,64]

    dim3 grid(B / BT), block(NTH);
    hipLaunchKernelGGL(lstm2_mfma, grid, block, 0, stream,
                       x, Wih0, Whh0, bih0, bhh0, Wih1, Whh1, bih1, bhh1,
                       Wout, bout, out, rlast);
}